// Round 1
// baseline (588.145 us; speedup 1.0000x reference)
//
#include <hip/hip_runtime.h>
#include <math.h>

// Problem geometry: B=64 images, each 1024*1024 fp32. C==1.
#define N_IMG        64
#define IMG_F4       (1u << 18)              // 262144 float4 per image
#define BLOCKS_PER_IMG 32
#define F4_PER_BLOCK (IMG_F4 / BLOCKS_PER_IMG)  // 8192
#define THREADS      256
#define ITERS        (F4_PER_BLOCK / THREADS)   // 32
#define N_TOTAL      67108864.0               // 64 * 1024 * 1024

__device__ __forceinline__ void atomicMinF(float* addr, float v) {
    if (v >= 0.f) atomicMin((int*)addr, __float_as_int(v));
    else          atomicMax((unsigned int*)addr, __float_as_uint(v));
}
__device__ __forceinline__ void atomicMaxF(float* addr, float v) {
    if (v >= 0.f) atomicMax((int*)addr, __float_as_int(v));
    else          atomicMin((unsigned int*)addr, __float_as_uint(v));
}

__global__ void init_ws(float* mn, float* mx, double* s_loss, double* s_w,
                        unsigned long long* cnt) {
    int i = threadIdx.x;
    if (i < N_IMG) { mn[i] = INFINITY; mx[i] = -INFINITY; }
    if (i == 0) { *s_loss = 0.0; *s_w = 0.0; *cnt = 0ull; }
}

// Pass 1: loss sum, avg_weight sum, per-image min/max.
__global__ __launch_bounds__(THREADS) void main_pass(
    const float4* __restrict__ in4, const float4* __restrict__ tg4,
    float* __restrict__ mn, float* __restrict__ mx,
    double* __restrict__ s_loss, double* __restrict__ s_w) {

    const int b   = blockIdx.x / BLOCKS_PER_IMG;
    const int blk = blockIdx.x % BLOCKS_PER_IMG;
    const unsigned base = (unsigned)b * IMG_F4 + (unsigned)blk * F4_PER_BLOCK + threadIdx.x;

    float lmin = INFINITY, lmax = -INFINITY;
    float lsum = 0.f, wsum = 0.f;

    for (int it = 0; it < ITERS; ++it) {
        float4 xv = in4[base + it * THREADS];
        float4 tv = tg4[base + it * THREADS];
        #pragma unroll
        for (int j = 0; j < 4; ++j) {
            float x = ((const float*)&xv)[j];
            float t = ((const float*)&tv)[j];

            float ax = fabsf(x);
            float e  = __expf(-ax);                     // in (0, 1]
            float q  = __builtin_amdgcn_rcpf(1.f + e);  // 1/(1+e)
            float p   = (x >= 0.f) ? q : e * q;         // sigmoid(x)
            float omp = (x >= 0.f) ? e * q : q;         // 1 - sigmoid(x)
            float L  = __logf(1.f + e);                 // log1p(exp(-|x|))
            float ls_pos = fminf(x, 0.f) - L;           // log_sigmoid(x)
            float ls_neg = -fmaxf(x, 0.f) - L;          // log_sigmoid(-x)

            float a  = t * (omp * omp);                 // target * (1-p)^2
            float bq = (1.f - t) * (p * p);             // (1-target) * p^2

            lsum -= a * ls_pos + bq * ls_neg;           // -= because loss = -( ... )
            wsum += a + bq;
            lmin = fminf(lmin, x);
            lmax = fmaxf(lmax, x);
        }
    }

    // wave (64-lane) butterfly reduce
    #pragma unroll
    for (int m = 32; m >= 1; m >>= 1) {
        lmin = fminf(lmin, __shfl_xor(lmin, m));
        lmax = fmaxf(lmax, __shfl_xor(lmax, m));
        lsum += __shfl_xor(lsum, m);
        wsum += __shfl_xor(wsum, m);
    }

    __shared__ float smin[4], smax[4], sls[4], sws[4];
    const int wave = threadIdx.x >> 6;
    if ((threadIdx.x & 63) == 0) {
        smin[wave] = lmin; smax[wave] = lmax; sls[wave] = lsum; sws[wave] = wsum;
    }
    __syncthreads();
    if (threadIdx.x == 0) {
        float bmin = smin[0], bmax = smax[0], bls = sls[0], bws = sws[0];
        #pragma unroll
        for (int w = 1; w < 4; ++w) {
            bmin = fminf(bmin, smin[w]); bmax = fmaxf(bmax, smax[w]);
            bls += sls[w]; bws += sws[w];
        }
        atomicMinF(&mn[b], bmin);
        atomicMaxF(&mx[b], bmax);
        atomicAdd(s_loss, (double)bls);
        atomicAdd(s_w,    (double)bws);
    }
}

// Pass 2: count norm > 0.8, i.e. x > mn + 0.8*(mx-mn), per image.
__global__ __launch_bounds__(THREADS) void count_pass(
    const float4* __restrict__ in4,
    const float* __restrict__ mn, const float* __restrict__ mx,
    unsigned long long* __restrict__ cnt) {

    const int b   = blockIdx.x / BLOCKS_PER_IMG;
    const int blk = blockIdx.x % BLOCKS_PER_IMG;
    const float lo = mn[b], hi = mx[b];
    const float thr = lo + 0.8f * (hi - lo);
    const unsigned base = (unsigned)b * IMG_F4 + (unsigned)blk * F4_PER_BLOCK + threadIdx.x;

    unsigned c = 0;
    for (int it = 0; it < ITERS; ++it) {
        float4 xv = in4[base + it * THREADS];
        c += (xv.x > thr) + (xv.y > thr) + (xv.z > thr) + (xv.w > thr);
    }

    #pragma unroll
    for (int m = 32; m >= 1; m >>= 1) c += __shfl_xor(c, m);

    __shared__ unsigned sc[4];
    const int wave = threadIdx.x >> 6;
    if ((threadIdx.x & 63) == 0) sc[wave] = c;
    __syncthreads();
    if (threadIdx.x == 0) {
        unsigned tot = sc[0] + sc[1] + sc[2] + sc[3];
        atomicAdd(cnt, (unsigned long long)tot);
    }
}

__global__ void finalize(const double* __restrict__ s_loss,
                         const double* __restrict__ s_w,
                         const unsigned long long* __restrict__ cnt,
                         float* __restrict__ out) {
    double frac = (double)(*cnt) / N_TOTAL;
    double ac   = pow(1.0 - frac, 1.5);   // (1 + MARGIN - frac)^ALPHA, MARGIN=0, ALPHA=1.5
    out[0] = (float)((*s_loss) / (*s_w) * ac);
}

extern "C" void kernel_launch(void* const* d_in, const int* in_sizes, int n_in,
                              void* d_out, int out_size, void* d_ws, size_t ws_size,
                              hipStream_t stream) {
    const float4* in4 = (const float4*)d_in[0];
    const float4* tg4 = (const float4*)d_in[1];

    char* ws = (char*)d_ws;
    double* s_loss = (double*)ws;                               // 8 B
    double* s_w    = (double*)(ws + 8);                         // 8 B
    unsigned long long* cnt = (unsigned long long*)(ws + 16);   // 8 B
    float* mn = (float*)(ws + 32);                              // 64 floats
    float* mx = (float*)(ws + 32 + 256);                        // 64 floats
    float* out = (float*)d_out;

    init_ws<<<1, 64, 0, stream>>>(mn, mx, s_loss, s_w, cnt);
    main_pass<<<N_IMG * BLOCKS_PER_IMG, THREADS, 0, stream>>>(in4, tg4, mn, mx, s_loss, s_w);
    count_pass<<<N_IMG * BLOCKS_PER_IMG, THREADS, 0, stream>>>(in4, mn, mx, cnt);
    finalize<<<1, 1, 0, stream>>>(s_loss, s_w, cnt, out);
}